// Round 5
// baseline (77.530 us; speedup 1.0000x reference)
//
#include <hip/hip_runtime.h>
#include <math.h>

// BoundaryLoss: out = mean |sigmoid(logits) - gt| * EDT_bg(gt)
// dist==0 exactly at gt==1  ->  |p-t|*dist == p*dist: targets only feed the
// fg bitmask.
// K1 pack: 8 px/thread -> fg byte -> LDS -> u32 word stores (+ zero d_out).
// K2 main: per 16-col stripe: prefetch logits -> registers, bitmask -> LDS,
//          clz/ffs exact row distances, early-exit exact vertical envelope,
//          fused sigmoid*dist reduce.

#define BB 16
#define HH 384
#define WW 384
#define WPR 12                 // u32 words per row
#define WPRP 13                // padded LDS stride (coprime 32: conflict-free)
#define SW 16                  // stripe width
#define NBLK (WW / SW)         // 24
#define THREADS 512
#define PTHREADS 512
#define SEGS 3                 // HH*(SW/4)/THREADS = 1536/512
#define BIGD 768

__global__ __launch_bounds__(PTHREADS) void pack_kernel(
    const int* __restrict__ gt, unsigned* __restrict__ mask,
    float* __restrict__ out) {
  __shared__ unsigned char s_byte[PTHREADS];
  const int base = blockIdx.x * PTHREADS * 8;        // 4096 px per block
  const int4* __restrict__ g4 = (const int4*)(gt + base);
  const int4 a = g4[threadIdx.x * 2];
  const int4 b = g4[threadIdx.x * 2 + 1];
  unsigned byte = (a.x != 0) | ((a.y != 0) << 1) | ((a.z != 0) << 2) |
                  ((a.w != 0) << 3) | ((b.x != 0) << 4) | ((b.y != 0) << 5) |
                  ((b.z != 0) << 6) | ((b.w != 0) << 7);
  s_byte[threadIdx.x] = (unsigned char)byte;
  __syncthreads();
  if (threadIdx.x < PTHREADS / 4) {                  // 128 u32 stores
    mask[(base >> 5) + threadIdx.x] = *(const unsigned*)(s_byte + threadIdx.x * 4);
  }
  if (blockIdx.x == 0 && threadIdx.x == 0) out[0] = 0.0f;
}

__global__ __launch_bounds__(THREADS) void boundary_loss_kernel(
    const float* __restrict__ logits, const unsigned* __restrict__ mask,
    float* __restrict__ out) {
  const int blk = blockIdx.x;
  const int b = blk / NBLK;
  const int j0 = (blk % NBLK) * SW;
  const float* __restrict__ lg = logits + b * HH * WW;

  __shared__ unsigned m_s[HH * WPRP];       // 19968 B
  __shared__ unsigned short g_s[HH * SW];   // 12288 B

  // ---- prefetch this thread's logits NOW; vmcnt drains behind phase 0/1 ----
  float4 xf[SEGS];
#pragma unroll
  for (int t = 0; t < SEGS; ++t) {
    const int s = threadIdx.x + t * THREADS;
    const int i = s >> 2;
    const int jj = (s & 3) * 4;
    xf[t] = *(const float4*)(lg + i * WW + j0 + jj);
  }

  // ---- stage fg bitmask: uint4 global loads, scalar LDS writes (padded) ----
  const uint4* __restrict__ gm4 = (const uint4*)(mask + b * HH * WPR);
  for (int s = threadIdx.x; s < HH * WPR / 4; s += THREADS) {  // 1152
    const uint4 v = gm4[s];
    const int row = s / 3;
    const int w0 = (s - row * 3) * 4;
    unsigned* dst = m_s + row * WPRP + w0;
    dst[0] = v.x; dst[1] = v.y; dst[2] = v.z; dst[3] = v.w;
  }
  __syncthreads();

  // ---- Phase 1: exact nearest-fg row distance, 4 cols/thread ----
#pragma unroll
  for (int t = 0; t < SEGS; ++t) {
    const int s = threadIdx.x + t * THREADS;
    const int i = s >> 2;
    const int jj = (s & 3) * 4;
    const int j = j0 + jj;                  // multiple of 4: 4 bits in one word
    const unsigned* __restrict__ mr = m_s + i * WPRP;
    const int w = j >> 5;
    const int bpos = j & 31;                // 0,4,...,28
    const unsigned cur = mr[w];

    int jL = -0x40000;
    if ((cur & (0xFFFFFFFFu >> (31 - bpos))) == 0u) {
      for (int ww = w - 1; ww >= 0; --ww) {
        const unsigned x = mr[ww];
        if (x) { jL = ww * 32 + 31 - __clz(x); break; }
      }
    }
    int jR = 0x40000;
    if ((cur & (0xFFFFFFFFu << (bpos + 3))) == 0u) {
      for (int ww = w + 1; ww < WPR; ++ww) {
        const unsigned x = mr[ww];
        if (x) { jR = ww * 32 + __ffs(x) - 1; break; }
      }
    }
    unsigned short g4[4];
#pragma unroll
    for (int c = 0; c < 4; ++c) {
      const int bc = bpos + c;
      const int jc = j + c;
      const unsigned lm = cur & (0xFFFFFFFFu >> (31 - bc));
      const unsigned rm = cur & (0xFFFFFFFFu << bc);
      const int dl = lm ? (bc - (31 - __clz(lm))) : (jc - jL);
      const int dr = rm ? ((__ffs(rm) - 1) - bc) : (jR - jc);
      g4[c] = (unsigned short)min(min(dl, dr), BIGD);
    }
    ushort4 gv; gv.x = g4[0]; gv.y = g4[1]; gv.z = g4[2]; gv.w = g4[3];
    *(ushort4*)(g_s + i * SW + jj) = gv;
  }
  __syncthreads();

  // ---- Phase 2: exact vertical envelope (early exit r*r >= best) + loss ----
  float acc = 0.0f;
#pragma unroll
  for (int t = 0; t < SEGS; ++t) {
    const int s = threadIdx.x + t * THREADS;
    const int i = s >> 2;
    const int jj = (s & 3) * 4;
    const ushort4 gv = *(const ushort4*)(g_s + i * SW + jj);
    const int gg[4] = {gv.x, gv.y, gv.z, gv.w};
    const float xs[4] = {xf[t].x, xf[t].y, xf[t].z, xf[t].w};
#pragma unroll
    for (int c = 0; c < 4; ++c) {
      int best = gg[c] * gg[c];
      for (int r = 1; r * r < best; ++r) {
        const int im = i - r, ip = i + r;
        if (im >= 0) { const int v = g_s[im * SW + jj + c]; best = min(best, r * r + v * v); }
        if (ip < HH) { const int v = g_s[ip * SW + jj + c]; best = min(best, r * r + v * v); }
      }
      const float dist = __builtin_amdgcn_sqrtf((float)best);       // rel ~1e-7
      const float p = __builtin_amdgcn_rcpf(1.0f + __expf(-xs[c])); // rel ~2.5e-7
      acc += p * dist;                        // == |p-t|*dist (dist=0 at fg)
    }
  }

  // ---- Block reduction -> one atomic per block ----
  __shared__ float red[THREADS / 64];
  for (int off = 32; off > 0; off >>= 1) acc += __shfl_down(acc, off, 64);
  const int lane = threadIdx.x & 63;
  const int wid = threadIdx.x >> 6;
  if (lane == 0) red[wid] = acc;
  __syncthreads();
  if (threadIdx.x == 0) {
    float ssum = 0.0f;
    for (int w = 0; w < THREADS / 64; ++w) ssum += red[w];
    atomicAdd(out, ssum * (1.0f / (float)(BB * HH * WW)));
  }
}

extern "C" void kernel_launch(void* const* d_in, const int* in_sizes, int n_in,
                              void* d_out, int out_size, void* d_ws, size_t ws_size,
                              hipStream_t stream) {
  const float* logits = (const float*)d_in[0];
  const int* targets = (const int*)d_in[1];
  float* out = (float*)d_out;
  unsigned* mask = (unsigned*)d_ws;       // 294912 B

  pack_kernel<<<(BB * HH * WW) / (PTHREADS * 8), PTHREADS, 0, stream>>>(targets, mask, out);
  boundary_loss_kernel<<<BB * NBLK, THREADS, 0, stream>>>(logits, mask, out);
}